// Round 1
// baseline (1514.501 us; speedup 1.0000x reference)
//
#include <hip/hip_runtime.h>
#include <math.h>

#define T_STEPS 512
#define HID 64

// --- cross-lane reduction over the 4 kq lanes (tid&3) via ds_swizzle butterfly ---
__device__ __forceinline__ float swz_xor1(float v) {
  return __int_as_float(__builtin_amdgcn_ds_swizzle(__float_as_int(v), 0x041F));
}
__device__ __forceinline__ float swz_xor2(float v) {
  return __int_as_float(__builtin_amdgcn_ds_swizzle(__float_as_int(v), 0x081F));
}
__device__ __forceinline__ float qred(float v) {
  v += swz_xor1(v);
  v += swz_xor2(v);
  return v;
}
// reduce each component over kq group, return the kq-th component (lane owns batch kq)
__device__ __forceinline__ float qred_sel(const float4& a, int kq) {
  float x = qred(a.x), y = qred(a.y), z = qred(a.z), w = qred(a.w);
  float lo = (kq & 1) ? y : x;
  float hi = (kq & 1) ? w : z;
  return (kq & 2) ? hi : lo;
}
__device__ __forceinline__ float sigm(float x) {
  return __builtin_amdgcn_rcpf(1.f + __expf(-x));
}
__device__ __forceinline__ float tanh_fast(float x) {
  return 1.f - 2.f * __builtin_amdgcn_rcpf(__expf(2.f * x) + 1.f);
}

#define FMA4(acc, s, v) do { \
    acc.x = fmaf((s), (v).x, acc.x); \
    acc.y = fmaf((s), (v).y, acc.y); \
    acc.z = fmaf((s), (v).z, acc.z); \
    acc.w = fmaf((s), (v).w, acc.w); } while (0)

// One WG = 4 batches, 256 threads. thread: j = tid>>2 (hidden unit), kq = tid&3 (k-chunk).
// All 4 GRU weight matrices live in registers (192 floats/thread).
// LDS layout for x / hA / hB: off(k) = k*4 + (k>>4)*4 (+b), pad breaks the
// 4-address bank aliasing of the kq-group b128 broadcast reads.
__global__ __launch_bounds__(256, 1) void gru_fused(
    const float* __restrict__ x,      // [1024][64][512]
    const float* __restrict__ Wih0, const float* __restrict__ Whh0,
    const float* __restrict__ bih0, const float* __restrict__ bhh0,
    const float* __restrict__ Wih1, const float* __restrict__ Whh1,
    const float* __restrict__ bih1, const float* __restrict__ bhh1,
    const float* __restrict__ W1, const float* __restrict__ b1,
    const float* __restrict__ W2, const float* __restrict__ b2,
    float* __restrict__ out)          // [1024][4]
{
  const int tid = threadIdx.x;
  const int j  = tid >> 2;
  const int kq = tid & 3;
  const int b0 = blockIdx.x << 2;

  __shared__ __align__(16) float xs_[272];
  __shared__ __align__(16) float hA_[272];
  __shared__ __align__(16) float hB_[272];
  __shared__ float msf[128];

  for (int idx = tid; idx < 272; idx += 256) { hA_[idx] = 0.f; hB_[idx] = 0.f; }

  // ---- load weights into registers (rows j, j+64, j+128; k-chunk kq*16..+15) ----
  float wiAr[16], wiAz[16], wiAn[16], whAr[16], whAz[16], whAn[16];
  float wiBr[16], wiBz[16], wiBn[16], whBr[16], whBz[16], whBn[16];
  {
    const int kb = kq * 16;
    #pragma unroll
    for (int q = 0; q < 4; ++q) {
      *(float4*)&wiAr[4*q] = *(const float4*)&Wih0[(j      ) * HID + kb + 4*q];
      *(float4*)&wiAz[4*q] = *(const float4*)&Wih0[(j +  64) * HID + kb + 4*q];
      *(float4*)&wiAn[4*q] = *(const float4*)&Wih0[(j + 128) * HID + kb + 4*q];
      *(float4*)&whAr[4*q] = *(const float4*)&Whh0[(j      ) * HID + kb + 4*q];
      *(float4*)&whAz[4*q] = *(const float4*)&Whh0[(j +  64) * HID + kb + 4*q];
      *(float4*)&whAn[4*q] = *(const float4*)&Whh0[(j + 128) * HID + kb + 4*q];
      *(float4*)&wiBr[4*q] = *(const float4*)&Wih1[(j      ) * HID + kb + 4*q];
      *(float4*)&wiBz[4*q] = *(const float4*)&Wih1[(j +  64) * HID + kb + 4*q];
      *(float4*)&wiBn[4*q] = *(const float4*)&Wih1[(j + 128) * HID + kb + 4*q];
      *(float4*)&whBr[4*q] = *(const float4*)&Whh1[(j      ) * HID + kb + 4*q];
      *(float4*)&whBz[4*q] = *(const float4*)&Whh1[(j +  64) * HID + kb + 4*q];
      *(float4*)&whBn[4*q] = *(const float4*)&Whh1[(j + 128) * HID + kb + 4*q];
    }
  }
  const float bAr  = bih0[j] + bhh0[j];
  const float bAz  = bih0[j+64] + bhh0[j+64];
  const float bAin = bih0[j+128];
  const float bAhn = bhh0[j+128];
  const float bBr  = bih1[j] + bhh1[j];
  const float bBz  = bih1[j+64] + bhh1[j+64];
  const float bBin = bih1[j+128];
  const float bBhn = bhh1[j+128];

  float hAreg = 0.f, hBreg = 0.f;   // this lane's h[b=kq][j]

  // x staging: thread loads x[b0 + (tid>>6)][tid&63][t] each step (64B line reused 16 steps in L1)
  const int sb = tid >> 6, si = tid & 63;
  const float* xptr = x + ((size_t)(b0 + sb) * HID + si) * T_STEPS;
  const int soff  = si*4 + (si>>4)*4 + sb;   // LDS write slot [k=si][b=sb]
  const int rbase = kq * 68;                 // = off(kq*16), 272B -> 16B aligned
  const int woff  = j*4 + (j>>4)*4 + kq;     // h write slot [k=j][b=kq]

  float xpre = xptr[0];

  #pragma unroll 1
  for (int t = 0; t < T_STEPS; ++t) {
    xs_[soff] = xpre;
    if (t < T_STEPS - 1) xpre = xptr[t + 1];   // uniform branch; prefetch next step
    __syncthreads();                           // (E) xs(t) + hB(t-1) visible

    // ---- layer 0: gates over k-chunk, all 4 batches ----
    float4 aR = make_float4(0,0,0,0), aZ = aR, aIN = aR, aHN = aR;
    #pragma unroll
    for (int i = 0; i < 16; ++i) {
      const float4 xv = *(const float4*)&xs_[rbase + 4*i];
      const float4 hv = *(const float4*)&hA_[rbase + 4*i];
      FMA4(aR, wiAr[i], xv);  FMA4(aR, whAr[i], hv);
      FMA4(aZ, wiAz[i], xv);  FMA4(aZ, whAz[i], hv);
      FMA4(aIN, wiAn[i], xv);
      FMA4(aHN, whAn[i], hv);
    }
    {
      const float ar  = qred_sel(aR,  kq) + bAr;
      const float az  = qred_sel(aZ,  kq) + bAz;
      const float ain = qred_sel(aIN, kq) + bAin;
      const float ahn = qred_sel(aHN, kq) + bAhn;
      const float r = sigm(ar);
      const float z = sigm(az);
      const float n = tanh_fast(fmaf(r, ahn, ain));
      hAreg = n + z * (hAreg - n);             // (1-z)*n + z*h
    }
    __syncthreads();                           // (A) all done reading old hA
    hA_[woff] = hAreg;
    __syncthreads();                           // (B) new hA visible

    // ---- layer 1: input = new hA, state = hB ----
    float4 cR = make_float4(0,0,0,0), cZ = cR, cIN = cR, cHN = cR;
    #pragma unroll
    for (int i = 0; i < 16; ++i) {
      const float4 uv = *(const float4*)&hA_[rbase + 4*i];
      const float4 hv = *(const float4*)&hB_[rbase + 4*i];
      FMA4(cR, wiBr[i], uv);  FMA4(cR, whBr[i], hv);
      FMA4(cZ, wiBz[i], uv);  FMA4(cZ, whBz[i], hv);
      FMA4(cIN, wiBn[i], uv);
      FMA4(cHN, whBn[i], hv);
    }
    {
      const float ar  = qred_sel(cR,  kq) + bBr;
      const float az  = qred_sel(cZ,  kq) + bBz;
      const float ain = qred_sel(cIN, kq) + bBin;
      const float ahn = qred_sel(cHN, kq) + bBhn;
      const float r = sigm(ar);
      const float z = sigm(az);
      const float n = tanh_fast(fmaf(r, ahn, ain));
      hBreg = n + z * (hBreg - n);
    }
    __syncthreads();                           // (C) all done reading old hB
    hB_[woff] = hBreg;
  }
  __syncthreads();

  // ---- classifier on final hB (once; cheap) ----
  if (tid < 128) {
    const int bb = tid >> 5, u = tid & 31;
    float acc = b1[u];
    const float* w1r = W1 + u * HID;
    #pragma unroll
    for (int k = 0; k < 64; ++k)
      acc = fmaf(w1r[k], hB_[k*4 + (k>>4)*4 + bb], acc);
    msf[(bb << 5) + u] = fmaxf(acc, 0.f);
  }
  __syncthreads();
  if (tid < 16) {
    const int bb = tid >> 2, c = tid & 3;
    float acc = b2[c];
    const float* w2r = W2 + (c << 5);
    #pragma unroll
    for (int u = 0; u < 32; ++u)
      acc = fmaf(w2r[u], msf[(bb << 5) + u], acc);
    out[(size_t)(b0 + bb) * 4 + c] = acc;
  }
}

extern "C" void kernel_launch(void* const* d_in, const int* in_sizes, int n_in,
                              void* d_out, int out_size, void* d_ws, size_t ws_size,
                              hipStream_t stream) {
  const float* x    = (const float*)d_in[0];
  const float* Wih0 = (const float*)d_in[1];
  const float* Whh0 = (const float*)d_in[2];
  const float* bih0 = (const float*)d_in[3];
  const float* bhh0 = (const float*)d_in[4];
  const float* Wih1 = (const float*)d_in[5];
  const float* Whh1 = (const float*)d_in[6];
  const float* bih1 = (const float*)d_in[7];
  const float* bhh1 = (const float*)d_in[8];
  const float* W1   = (const float*)d_in[9];
  const float* b1   = (const float*)d_in[10];
  const float* W2   = (const float*)d_in[11];
  const float* b2   = (const float*)d_in[12];
  float* out = (float*)d_out;

  hipLaunchKernelGGL(gru_fused, dim3(256), dim3(256), 0, stream,
                     x, Wih0, Whh0, bih0, bhh0, Wih1, Whh1, bih1, bhh1,
                     W1, b1, W2, b2, out);
}

// Round 2
// 1024.148 us; speedup vs baseline: 1.4788x; 1.4788x over previous
//
#include <hip/hip_runtime.h>
#include <math.h>

#define T_STEPS 512
#define HID 64

// ---- cross-lane helpers ----
// DPP quad_perm xor1 / xor2 (VALU pipe, folds into v_add_f32_dpp)
__device__ __forceinline__ float dpp_xor1(float v) {
  return __int_as_float(__builtin_amdgcn_update_dpp(0, __float_as_int(v), 0xB1, 0xf, 0xf, true));
}
__device__ __forceinline__ float dpp_xor2(float v) {
  return __int_as_float(__builtin_amdgcn_update_dpp(0, __float_as_int(v), 0x4E, 0xf, 0xf, true));
}
// ds_swizzle xor4 (groups of 8 never cross the 32-lane swizzle domain)
__device__ __forceinline__ float swz_xor4(float v) {
  return __int_as_float(__builtin_amdgcn_ds_swizzle(__float_as_int(v), 0x101F));
}

// a = float4 of per-batch partial sums; 8 lanes (kq8=lane&7) hold k-chunk partials.
// Returns: lane gets the full 8-lane sum of component (kq8&3).
// Component-paired butterfly: xor1 pairs (x,y),(z,w); xor2 pairs (u,v); xor4 full.
__device__ __forceinline__ float qred8_sel(const float4& a, int kq8) {
  const bool b0 = kq8 & 1;
  const bool b1 = (kq8 & 2) != 0;
  float u = (b0 ? a.y : a.x) + dpp_xor1(b0 ? a.x : a.y);
  float v = (b0 ? a.w : a.z) + dpp_xor1(b0 ? a.z : a.w);
  float r = (b1 ? v : u) + dpp_xor2(b1 ? u : v);
  r += swz_xor4(r);
  return r;
}

__device__ __forceinline__ float sigm(float x) {
  return __builtin_amdgcn_rcpf(1.f + __expf(-x));
}
__device__ __forceinline__ float tanh_fast(float x) {
  return 1.f - 2.f * __builtin_amdgcn_rcpf(__expf(2.f * x) + 1.f);
}

#define FMA4(acc, s, v) do { \
    acc.x = fmaf((s), (v).x, acc.x); \
    acc.y = fmaf((s), (v).y, acc.y); \
    acc.z = fmaf((s), (v).z, acc.z); \
    acc.w = fmaf((s), (v).w, acc.w); } while (0)

__device__ __forceinline__ void accum_layer(
    const float* inb, const float* hb,
    const float* wi_r, const float* wi_z, const float* wi_n,
    const float* wh_r, const float* wh_z, const float* wh_n,
    float4& aR, float4& aZ, float4& aIN, float4& aHN)
{
  #pragma unroll
  for (int i = 0; i < 8; ++i) {
    const float4 xv = *(const float4*)(inb + 4 * i);
    const float4 hv = *(const float4*)(hb + 4 * i);
    FMA4(aR, wi_r[i], xv);  FMA4(aR, wh_r[i], hv);
    FMA4(aZ, wi_z[i], xv);  FMA4(aZ, wh_z[i], hv);
    FMA4(aIN, wi_n[i], xv);
    FMA4(aHN, wh_n[i], hv);
  }
}

__device__ __forceinline__ float gru_update(
    const float4& aR, const float4& aZ, const float4& aIN, const float4& aHN,
    float br, float bz, float bin, float bhn, int kq8, float h)
{
  const float ar  = qred8_sel(aR,  kq8) + br;
  const float az  = qred8_sel(aZ,  kq8) + bz;
  const float ain = qred8_sel(aIN, kq8) + bin;
  const float ahn = qred8_sel(aHN, kq8) + bhn;
  const float r = sigm(ar);
  const float z = sigm(az);
  const float n = tanh_fast(fmaf(r, ahn, ain));
  return n + z * (h - n);
}

// WG = 512 threads (8 waves/CU), 4 batches/WG, grid = 256.
// thread: j = tid>>3 (hidden row), kq8 = tid&7 (8-float k-chunk). Lanes kq8 and
// kq8^4 duplicate the h[b=kq8&3][j] update (harmless, avoids divergence).
// LDS value V[k][b] at word 4k + 4*(k>>3) + b: the 8 kq-group b128 reads land on
// 8 distinct bank quads (conflict-free); 16B alignment holds (144*kq8 bytes).
// Double-buffered xs/hA/hB -> 2 barriers per step.
__global__ __launch_bounds__(512, 2) void gru_fused(
    const float* __restrict__ x,      // [1024][64][512]
    const float* __restrict__ Wih0, const float* __restrict__ Whh0,
    const float* __restrict__ bih0, const float* __restrict__ bhh0,
    const float* __restrict__ Wih1, const float* __restrict__ Whh1,
    const float* __restrict__ bih1, const float* __restrict__ bhh1,
    const float* __restrict__ W1, const float* __restrict__ b1,
    const float* __restrict__ W2, const float* __restrict__ b2,
    float* __restrict__ out)          // [1024][4]
{
  const int tid = threadIdx.x;
  const int j   = tid >> 3;
  const int kq8 = tid & 7;
  const int b0  = blockIdx.x << 2;

  __shared__ __align__(16) float xs_[2][288];
  __shared__ __align__(16) float hA_[2][288];
  __shared__ __align__(16) float hB_[2][288];
  __shared__ float msf[128];

  // ---- weights into registers: rows j, j+64, j+128; k-chunk kq8*8..+7 ----
  float wiAr[8], wiAz[8], wiAn[8], whAr[8], whAz[8], whAn[8];
  float wiBr[8], wiBz[8], wiBn[8], whBr[8], whBz[8], whBn[8];
  {
    const int kb = kq8 * 8;
    #define LD8(dst, W, row) do { \
        *(float4*)&dst[0] = *(const float4*)&W[(row) * HID + kb]; \
        *(float4*)&dst[4] = *(const float4*)&W[(row) * HID + kb + 4]; } while (0)
    LD8(wiAr, Wih0, j); LD8(wiAz, Wih0, j + 64); LD8(wiAn, Wih0, j + 128);
    LD8(whAr, Whh0, j); LD8(whAz, Whh0, j + 64); LD8(whAn, Whh0, j + 128);
    LD8(wiBr, Wih1, j); LD8(wiBz, Wih1, j + 64); LD8(wiBn, Wih1, j + 128);
    LD8(whBr, Whh1, j); LD8(whBz, Whh1, j + 64); LD8(whBn, Whh1, j + 128);
    #undef LD8
  }
  const float bAr  = bih0[j] + bhh0[j];
  const float bAz  = bih0[j + 64] + bhh0[j + 64];
  const float bAin = bih0[j + 128];
  const float bAhn = bhh0[j + 128];
  const float bBr  = bih1[j] + bhh1[j];
  const float bBz  = bih1[j + 64] + bhh1[j + 64];
  const float bBin = bih1[j + 128];
  const float bBhn = bhh1[j + 128];

  const int rbase = 36 * kq8;                       // read base (words), 16B aligned
  const int whoff = 4 * j + 4 * (j >> 3) + (kq8 & 3); // h write slot [k=j][b]

  // x staging: threads tid<256: c = tid>>2, b_s = tid&3
  const int sc = tid >> 2, sb = tid & 3;
  const float* xptr = x + ((size_t)(b0 + sb) * HID + sc) * T_STEPS;
  const int soff = 4 * sc + 4 * (sc >> 3) + sb;

  float xpre = 0.f;
  if (tid < 256) {
    xs_[0][soff] = xptr[0];
    xpre = xptr[1];
  }
  for (int idx = tid; idx < 288; idx += 512) { hA_[0][idx] = 0.f; hB_[0][idx] = 0.f; }

  float hAreg = 0.f, hBreg = 0.f;
  __syncthreads();

  #define STEP(CUR, NXT, TCUR) do { \
      if (tid < 256) { \
        xs_[NXT][soff] = xpre; \
        if ((TCUR) < T_STEPS - 2) xpre = xptr[(TCUR) + 2]; \
      } \
      { float4 aR = make_float4(0,0,0,0), aZ = aR, aIN = aR, aHN = aR; \
        accum_layer(&xs_[CUR][rbase], &hA_[CUR][rbase], \
                    wiAr, wiAz, wiAn, whAr, whAz, whAn, aR, aZ, aIN, aHN); \
        hAreg = gru_update(aR, aZ, aIN, aHN, bAr, bAz, bAin, bAhn, kq8, hAreg); \
        hA_[NXT][whoff] = hAreg; } \
      __syncthreads(); \
      { float4 cR = make_float4(0,0,0,0), cZ = cR, cIN = cR, cHN = cR; \
        accum_layer(&hA_[NXT][rbase], &hB_[CUR][rbase], \
                    wiBr, wiBz, wiBn, whBr, whBz, whBn, cR, cZ, cIN, cHN); \
        hBreg = gru_update(cR, cZ, cIN, cHN, bBr, bBz, bBin, bBhn, kq8, hBreg); \
        hB_[NXT][whoff] = hBreg; } \
      __syncthreads(); \
    } while (0)

  #pragma unroll 1
  for (int t = 0; t < T_STEPS; t += 2) {
    STEP(0, 1, t);
    STEP(1, 0, t + 1);
  }
  #undef STEP

  // final hB lives in buffer 0 (t=511 wrote nxt=0)
  if (tid < 128) {
    const int bb = tid >> 5, u = tid & 31;
    float acc = b1[u];
    const float* w1r = W1 + u * HID;
    #pragma unroll
    for (int k = 0; k < 64; ++k)
      acc = fmaf(w1r[k], hB_[0][4 * k + 4 * (k >> 3) + bb], acc);
    msf[(bb << 5) + u] = fmaxf(acc, 0.f);
  }
  __syncthreads();
  if (tid < 16) {
    const int bb = tid >> 2, c = tid & 3;
    float acc = b2[c];
    const float* w2r = W2 + (c << 5);
    #pragma unroll
    for (int u = 0; u < 32; ++u)
      acc = fmaf(w2r[u], msf[(bb << 5) + u], acc);
    out[(size_t)(b0 + bb) * 4 + c] = acc;
  }
}

extern "C" void kernel_launch(void* const* d_in, const int* in_sizes, int n_in,
                              void* d_out, int out_size, void* d_ws, size_t ws_size,
                              hipStream_t stream) {
  const float* x    = (const float*)d_in[0];
  const float* Wih0 = (const float*)d_in[1];
  const float* Whh0 = (const float*)d_in[2];
  const float* bih0 = (const float*)d_in[3];
  const float* bhh0 = (const float*)d_in[4];
  const float* Wih1 = (const float*)d_in[5];
  const float* Whh1 = (const float*)d_in[6];
  const float* bih1 = (const float*)d_in[7];
  const float* bhh1 = (const float*)d_in[8];
  const float* W1   = (const float*)d_in[9];
  const float* b1   = (const float*)d_in[10];
  const float* W2   = (const float*)d_in[11];
  const float* b2   = (const float*)d_in[12];
  float* out = (float*)d_out;

  hipLaunchKernelGGL(gru_fused, dim3(256), dim3(512), 0, stream,
                     x, Wih0, Whh0, bih0, bhh0, Wih1, Whh1, bih1, bhh1,
                     W1, b1, W2, b2, out);
}